// Round 1
// baseline (2150.006 us; speedup 1.0000x reference)
//
#include <hip/hip_runtime.h>

#define EPSV 1e-5f

// ---------------------------------------------------------------------------
// Stage-1 GEMM (NT): Y[b][o][c] = relu(bn(sum_s W[o][s] * X[b][c][s]))
// W: [O][S] row-major, X: [B][C][S], Y: [B][O][C]
// Tiles: BM=64 (o), BN=64 (c), BK=16 (s). 256 threads, 4x4 micro-tile.
// ---------------------------------------------------------------------------
__global__ __launch_bounds__(256)
void gemm_nt_bn(const float* __restrict__ W, const float* __restrict__ X,
                const float* __restrict__ bn, float* __restrict__ Y,
                int O, int C, int S)
{
    const int b  = blockIdx.z;
    const int o0 = blockIdx.y * 64;
    const int c0 = blockIdx.x * 64;
    const float* __restrict__ Xb = X + (size_t)b * C * S;

    __shared__ float As[16][68];   // [k][m], pad->row stride 68 (float4-aligned)
    __shared__ float Bs[16][68];   // [k][n]

    const int tid  = threadIdx.x;
    const int lrow = tid >> 2;          // 0..63 tile row
    const int lc4  = (tid & 3) << 2;    // 0,4,8,12 k-offset
    const int tx = tid & 15;            // n micro
    const int ty = tid >> 4;            // m micro

    float acc[4][4] = {};

    for (int s0 = 0; s0 < S; s0 += 16) {
        const float4 av = *(const float4*)&W [(size_t)(o0 + lrow) * S + s0 + lc4];
        const float4 bv = *(const float4*)&Xb[(size_t)(c0 + lrow) * S + s0 + lc4];
        __syncthreads();
        As[lc4 + 0][lrow] = av.x; As[lc4 + 1][lrow] = av.y;
        As[lc4 + 2][lrow] = av.z; As[lc4 + 3][lrow] = av.w;
        Bs[lc4 + 0][lrow] = bv.x; Bs[lc4 + 1][lrow] = bv.y;
        Bs[lc4 + 2][lrow] = bv.z; Bs[lc4 + 3][lrow] = bv.w;
        __syncthreads();
#pragma unroll
        for (int k = 0; k < 16; ++k) {
            float a[4], bb[4];
            *(float4*)a  = *(const float4*)&As[k][ty << 2];
            *(float4*)bb = *(const float4*)&Bs[k][tx << 2];
#pragma unroll
            for (int i = 0; i < 4; ++i)
#pragma unroll
                for (int j = 0; j < 4; ++j)
                    acc[i][j] = fmaf(a[i], bb[j], acc[i][j]);
        }
    }

    float* __restrict__ Yb = Y + (size_t)b * O * C;
#pragma unroll
    for (int i = 0; i < 4; ++i) {
        const int o = o0 + (ty << 2) + i;
        const float g = bn[o], be = bn[O + o], m = bn[2 * O + o], v = bn[3 * O + o];
        const float sc = g / sqrtf(v + EPSV);
        const float sh = be - m * sc;
        float4 r;
        r.x = fmaxf(acc[i][0] * sc + sh, 0.f);
        r.y = fmaxf(acc[i][1] * sc + sh, 0.f);
        r.z = fmaxf(acc[i][2] * sc + sh, 0.f);
        r.w = fmaxf(acc[i][3] * sc + sh, 0.f);
        *(float4*)&Yb[(size_t)o * C + c0 + (tx << 2)] = r;
    }
}

// ---------------------------------------------------------------------------
// Gc GEMM (TN): Cmat[b][m][n] = sum_k A[b][k][m] * B[b][k][n]
// A = y_theta [B][K=576][M=512], B = y_phi [B][576][512]
// ---------------------------------------------------------------------------
__global__ __launch_bounds__(256)
void gemm_tn(const float* __restrict__ A, const float* __restrict__ B,
             float* __restrict__ Cmat, int M, int N, int K)
{
    const int b  = blockIdx.z;
    const int m0 = blockIdx.y * 64;
    const int n0 = blockIdx.x * 64;
    const float* __restrict__ Ab = A + (size_t)b * K * M;
    const float* __restrict__ Bb = B + (size_t)b * K * N;

    __shared__ float As[16][68];
    __shared__ float Bs[16][68];

    const int tid = threadIdx.x;
    const int lk  = tid >> 4;           // 0..15
    const int lm4 = (tid & 15) << 2;    // 0..60
    const int tx = tid & 15;
    const int ty = tid >> 4;

    float acc[4][4] = {};

    for (int k0 = 0; k0 < K; k0 += 16) {
        const float4 av = *(const float4*)&Ab[(size_t)(k0 + lk) * M + m0 + lm4];
        const float4 bv = *(const float4*)&Bb[(size_t)(k0 + lk) * N + n0 + lm4];
        __syncthreads();
        *(float4*)&As[lk][lm4] = av;
        *(float4*)&Bs[lk][lm4] = bv;
        __syncthreads();
#pragma unroll
        for (int k = 0; k < 16; ++k) {
            float a[4], bb[4];
            *(float4*)a  = *(const float4*)&As[k][ty << 2];
            *(float4*)bb = *(const float4*)&Bs[k][tx << 2];
#pragma unroll
            for (int i = 0; i < 4; ++i)
#pragma unroll
                for (int j = 0; j < 4; ++j)
                    acc[i][j] = fmaf(a[i], bb[j], acc[i][j]);
        }
    }

    float* __restrict__ Cb = Cmat + (size_t)b * M * N;
#pragma unroll
    for (int i = 0; i < 4; ++i) {
        const int m = m0 + (ty << 2) + i;
        float4 r;
        r.x = acc[i][0]; r.y = acc[i][1]; r.z = acc[i][2]; r.w = acc[i][3];
        *(float4*)&Cb[(size_t)m * N + n0 + (tx << 2)] = r;
    }
}

// ---------------------------------------------------------------------------
// gg: GG[b][i][d] = relu(bn(sum_{j<512} Wgg[i][j]*Gc[b][d][j]
//                        + sum_{j<512} Wgg[i][512+j]*Gc[b][j][d]))
// ---------------------------------------------------------------------------
__global__ __launch_bounds__(256)
void gemm_gg(const float* __restrict__ Wgg, const float* __restrict__ Gc,
             const float* __restrict__ bn, float* __restrict__ GG,
             int IC, int D)
{
    const int b  = blockIdx.z;
    const int i0 = blockIdx.y * 64;
    const int d0 = blockIdx.x * 64;
    const float* __restrict__ Gb = Gc + (size_t)b * D * D;

    __shared__ float A1s[16][68], B1s[16][68], A2s[16][68], B2s[16][68];

    const int tid  = threadIdx.x;
    const int lrow = tid >> 2;          // NT-load row
    const int lc4  = (tid & 3) << 2;    // NT-load k-offset
    const int lk   = tid >> 4;          // TN-load k
    const int lm4  = (tid & 15) << 2;   // TN-load col
    const int tx = tid & 15;
    const int ty = tid >> 4;

    float acc[4][4] = {};

    for (int j0 = 0; j0 < 512; j0 += 16) {
        const float4 a1 = *(const float4*)&Wgg[(size_t)(i0 + lrow) * 1024 + j0 + lc4];
        const float4 a2 = *(const float4*)&Wgg[(size_t)(i0 + lrow) * 1024 + 512 + j0 + lc4];
        const float4 b1 = *(const float4*)&Gb[(size_t)(d0 + lrow) * D + j0 + lc4];
        const float4 b2 = *(const float4*)&Gb[(size_t)(j0 + lk) * D + d0 + lm4];
        __syncthreads();
        A1s[lc4 + 0][lrow] = a1.x; A1s[lc4 + 1][lrow] = a1.y;
        A1s[lc4 + 2][lrow] = a1.z; A1s[lc4 + 3][lrow] = a1.w;
        A2s[lc4 + 0][lrow] = a2.x; A2s[lc4 + 1][lrow] = a2.y;
        A2s[lc4 + 2][lrow] = a2.z; A2s[lc4 + 3][lrow] = a2.w;
        B1s[lc4 + 0][lrow] = b1.x; B1s[lc4 + 1][lrow] = b1.y;
        B1s[lc4 + 2][lrow] = b1.z; B1s[lc4 + 3][lrow] = b1.w;
        *(float4*)&B2s[lk][lm4] = b2;
        __syncthreads();
#pragma unroll
        for (int k = 0; k < 16; ++k) {
            float a1v[4], b1v[4], a2v[4], b2v[4];
            *(float4*)a1v = *(const float4*)&A1s[k][ty << 2];
            *(float4*)b1v = *(const float4*)&B1s[k][tx << 2];
            *(float4*)a2v = *(const float4*)&A2s[k][ty << 2];
            *(float4*)b2v = *(const float4*)&B2s[k][tx << 2];
#pragma unroll
            for (int i = 0; i < 4; ++i)
#pragma unroll
                for (int j = 0; j < 4; ++j)
                    acc[i][j] = fmaf(a1v[i], b1v[j], fmaf(a2v[i], b2v[j], acc[i][j]));
        }
    }

    float* __restrict__ Gout = GG + (size_t)b * IC * D;
#pragma unroll
    for (int i = 0; i < 4; ++i) {
        const int irow = i0 + (ty << 2) + i;
        const float g = bn[irow], be = bn[IC + irow], m = bn[2 * IC + irow], v = bn[3 * IC + irow];
        const float sc = g / sqrtf(v + EPSV);
        const float sh = be - m * sc;
        float4 r;
        r.x = fmaxf(acc[i][0] * sc + sh, 0.f);
        r.y = fmaxf(acc[i][1] * sc + sh, 0.f);
        r.z = fmaxf(acc[i][2] * sc + sh, 0.f);
        r.w = fmaxf(acc[i][3] * sc + sh, 0.f);
        *(float4*)&Gout[(size_t)irow * D + d0 + (tx << 2)] = r;
    }
}

// ---------------------------------------------------------------------------
// mean over o: g[b][c] = (1/O) * sum_o Y[b][o][c]
// ---------------------------------------------------------------------------
__global__ __launch_bounds__(256)
void reduce_mean(const float* __restrict__ Y, float* __restrict__ g, int O, int C)
{
    const int b = blockIdx.z;
    const int c = blockIdx.x * 256 + threadIdx.x;
    const float* __restrict__ Yb = Y + (size_t)b * O * C;
    float s = 0.f;
    for (int o = 0; o < O; ++o) s += Yb[(size_t)o * C + c];
    g[b * C + c] = s * (1.0f / O);
}

// ---------------------------------------------------------------------------
// gate[b][d] = sigmoid(bn2(sum_o Wc2[o]*relu(bn1(sum_j Wc1[o][j]*yc[b][j][d]))))
// yc[b][0][d]=gxc[b][d]; yc[b][1+i][d]=GG[b][i][d].  d-tile=64, 256 threads.
// ---------------------------------------------------------------------------
__global__ __launch_bounds__(256)
void gate_kernel(const float* __restrict__ gxc, const float* __restrict__ GG,
                 const float* __restrict__ Wc1, const float* __restrict__ bn1,
                 const float* __restrict__ Wc2, const float* __restrict__ bn2,
                 float* __restrict__ gate, int IC, int D, int OC)
{
    const int b  = blockIdx.y;
    const int d0 = blockIdx.x * 64;

    __shared__ float yc_s[129][64];
    __shared__ float part[4][64];

    const int tid = threadIdx.x;
    for (int idx = tid; idx < 129 * 64; idx += 256) {
        const int j = idx >> 6, d = idx & 63;
        yc_s[j][d] = (j == 0) ? gxc[b * D + d0 + d]
                              : GG[((size_t)b * IC + (j - 1)) * D + d0 + d];
    }
    __syncthreads();

    const int d = tid & 63;
    const int q = tid >> 6;           // 0..3
    float acc2 = 0.f;
    for (int o = q * 16; o < q * 16 + 16; ++o) {
        float s = 0.f;
        const float* __restrict__ w = &Wc1[o * 129];
        for (int j = 0; j < 129; ++j) s = fmaf(w[j], yc_s[j][d], s);
        const float g1 = bn1[o], be1 = bn1[OC + o], m1 = bn1[2 * OC + o], v1 = bn1[3 * OC + o];
        const float sc = g1 / sqrtf(v1 + EPSV);
        const float w1 = fmaxf(s * sc + (be1 - m1 * sc), 0.f);
        acc2 = fmaf(Wc2[o], w1, acc2);
    }
    part[q][d] = acc2;
    __syncthreads();
    if (q == 0) {
        const float s = part[0][d] + part[1][d] + part[2][d] + part[3][d];
        const float g2 = bn2[0], be2 = bn2[1], m2 = bn2[2], v2 = bn2[3];
        const float sc = g2 / sqrtf(v2 + EPSV);
        const float wy = s * sc + (be2 - m2 * sc);
        gate[b * D + d0 + d] = 1.f / (1.f + expf(-wy));
    }
}

// ---------------------------------------------------------------------------
// out = x * (1 + gate[b][c]), vectorized float4
// ---------------------------------------------------------------------------
__global__ __launch_bounds__(256)
void final_kernel(const float* __restrict__ x, const float* __restrict__ gate,
                  float* __restrict__ out, long n4, int sp4)
{
    long i = (long)blockIdx.x * blockDim.x + threadIdx.x;
    const long stride = (long)gridDim.x * blockDim.x;
    for (; i < n4; i += stride) {
        float4 v = ((const float4*)x)[i];
        const long bc = i / sp4;               // b*512 + c
        const float gm = 1.f + gate[bc];
        v.x *= gm; v.y *= gm; v.z *= gm; v.w *= gm;
        ((float4*)out)[i] = v;
    }
}

// ---------------------------------------------------------------------------
extern "C" void kernel_launch(void* const* d_in, const int* in_sizes, int n_in,
                              void* d_out, int out_size, void* d_ws, size_t ws_size,
                              hipStream_t stream)
{
    const float* x        = (const float*)d_in[0];
    const float* W_theta  = (const float*)d_in[1];
    const float* bn_theta = (const float*)d_in[2];
    const float* W_phi    = (const float*)d_in[3];
    const float* bn_phi   = (const float*)d_in[4];
    const float* W_gx     = (const float*)d_in[5];
    const float* bn_gx    = (const float*)d_in[6];
    const float* W_gg     = (const float*)d_in[7];
    const float* bn_gg    = (const float*)d_in[8];
    const float* W_c1     = (const float*)d_in[9];
    const float* bn_c1    = (const float*)d_in[10];
    const float* W_c2     = (const float*)d_in[11];
    const float* bn_c2    = (const float*)d_in[12];
    float* out = (float*)d_out;

    const int B = 32, C = 512, S = 2304, O = 576, IC = 128, OC = 64;

    // Big intermediates live inside d_out (dead before final elementwise pass):
    //   bufA: y_gx then y_theta [B][O][C] = 9,437,184 floats
    //   bufB: y_phi             [B][O][C] = 9,437,184 floats
    //   Gc  :                   [B][C][C] = 8,388,608 floats
    // total 27,262,976 <= out_size (37,748,736).
    float* bufA = out;
    float* bufB = bufA + (size_t)B * O * C;
    float* Gc   = bufB + (size_t)B * O * C;
    // Small intermediates in ws (~8.5 MB).
    float* ws   = (float*)d_ws;
    float* GG   = ws;                               // B*IC*C = 2,097,152
    float* gxc  = GG + (size_t)B * IC * C;          // B*C
    float* gate = gxc + (size_t)B * C;              // B*C

    const dim3 blk(256);
    const dim3 g1(C / 64, O / 64, B);               // stage-1 gemms

    // 1) y_gx -> bufA ; column mean -> gxc
    gemm_nt_bn<<<g1, blk, 0, stream>>>(W_gx, x, bn_gx, bufA, O, C, S);
    reduce_mean<<<dim3(C / 256, 1, B), blk, 0, stream>>>(bufA, gxc, O, C);
    // 2) y_theta -> bufA (overwrite), y_phi -> bufB
    gemm_nt_bn<<<g1, blk, 0, stream>>>(W_theta, x, bn_theta, bufA, O, C, S);
    gemm_nt_bn<<<g1, blk, 0, stream>>>(W_phi, x, bn_phi, bufB, O, C, S);
    // 3) Gc = y_theta^T * y_phi
    gemm_tn<<<dim3(C / 64, C / 64, B), blk, 0, stream>>>(bufA, bufB, Gc, C, C, O);
    // 4) GG = relu(bn(W_gg * [Gc^T ; Gc]))
    gemm_gg<<<dim3(C / 64, IC / 64, B), blk, 0, stream>>>(W_gg, Gc, bn_gg, GG, IC, C);
    // 5) gate
    gate_kernel<<<dim3(C / 64, B), blk, 0, stream>>>(gxc, GG, W_c1, bn_c1, W_c2, bn_c2,
                                                     gate, IC, C, OC);
    // 6) out = x * (1 + gate)
    final_kernel<<<dim3(2048), blk, 0, stream>>>(x, gate, out,
                                                 (long)B * C * S / 4, S / 4);
}

// Round 2
// 996.188 us; speedup vs baseline: 2.1582x; 2.1582x over previous
//
#include <hip/hip_runtime.h>
#include <cstdint>

#define EPSV 1e-5f
typedef unsigned short u16;
typedef __attribute__((ext_vector_type(8))) short bh8;   // 8 bf16 (4 VGPRs)
typedef __attribute__((ext_vector_type(4))) float f4;

__device__ __forceinline__ float bf2f(u16 h) { return __uint_as_float((unsigned)h << 16); }
__device__ __forceinline__ u16 f2bf(float x) {
    unsigned u = __float_as_uint(x);
    u += 0x7fffu + ((u >> 16) & 1u);          // RNE
    return (u16)(u >> 16);
}

// async global->LDS, 16B per lane; LDS dest = wave-uniform base + lane*16
__device__ __forceinline__ void gl16(const void* g, const void* s) {
    __builtin_amdgcn_global_load_lds(
        reinterpret_cast<const __attribute__((address_space(1))) void*>((uintptr_t)g),
        reinterpret_cast<__attribute__((address_space(3))) void*>((unsigned)(uintptr_t)s),
        16, 0, 0);
}

// ---------------------------------------------------------------------------
// Shared NT hi/lo GEMM core: C(128x128) += A(128xK) * B(128xK)^T, both K-major.
// acc = sum over k of (Ahi+Alo)*(Bhi+Blo) ~ 3 MFMA combos (hi*hi+hi*lo+lo*hi).
// 256 threads = 4 waves (2x2), each wave 64x64 via 4x4 frags of 16x16x32.
// ---------------------------------------------------------------------------
__device__ __forceinline__ void gemm_core(
    const u16* __restrict__ Ah, const u16* __restrict__ Al,
    const u16* __restrict__ Bh, const u16* __restrict__ Bl,
    long ldK, int K, int rowA0, int rowB0,
    u16* sAh, u16* sAl, u16* sBh, u16* sBl,
    f4 acc[4][4])
{
    const int tid = threadIdx.x, l = tid & 63, w = tid >> 6;
    const int ch0 = w * 64 + l;
    const int r0 = ch0 >> 2, c0 = (ch0 & 3) << 3;     // staging row/col (q=0)
    const int r1 = r0 + 64;                           // q=1: same col
    const int wr = w >> 1, wc = w & 1;
    const int lk = (l >> 4) << 3, lm = l & 15;
    const char* bA = (const char*)sAh + w * 1024;
    const char* bAl = (const char*)sAl + w * 1024;
    const char* bB = (const char*)sBh + w * 1024;
    const char* bBl = (const char*)sBl + w * 1024;

    for (int s0 = 0; s0 < K; s0 += 32) {
        if (s0) __syncthreads();
        gl16(Ah + (size_t)(rowA0 + r0) * ldK + s0 + c0, bA);
        gl16(Ah + (size_t)(rowA0 + r1) * ldK + s0 + c0, bA + 4096);
        gl16(Al + (size_t)(rowA0 + r0) * ldK + s0 + c0, bAl);
        gl16(Al + (size_t)(rowA0 + r1) * ldK + s0 + c0, bAl + 4096);
        gl16(Bh + (size_t)(rowB0 + r0) * ldK + s0 + c0, bB);
        gl16(Bh + (size_t)(rowB0 + r1) * ldK + s0 + c0, bB + 4096);
        gl16(Bl + (size_t)(rowB0 + r0) * ldK + s0 + c0, bBl);
        gl16(Bl + (size_t)(rowB0 + r1) * ldK + s0 + c0, bBl + 4096);
        __syncthreads();   // compiler drains vmcnt(0) before s_barrier -> tiles ready

        bh8 a_h[4], a_l[4], b_h[4], b_l[4];
#pragma unroll
        for (int i = 0; i < 4; ++i) {
            const int ar = (wr * 64 + i * 16 + lm) * 32 + lk;
            const int br = (wc * 64 + i * 16 + lm) * 32 + lk;
            a_h[i] = *(const bh8*)&sAh[ar];
            a_l[i] = *(const bh8*)&sAl[ar];
            b_h[i] = *(const bh8*)&sBh[br];
            b_l[i] = *(const bh8*)&sBl[br];
        }
#pragma unroll
        for (int i = 0; i < 4; ++i)
#pragma unroll
            for (int j = 0; j < 4; ++j) {
                acc[i][j] = __builtin_amdgcn_mfma_f32_16x16x32_bf16(a_h[i], b_h[j], acc[i][j], 0, 0, 0);
                acc[i][j] = __builtin_amdgcn_mfma_f32_16x16x32_bf16(a_h[i], b_l[j], acc[i][j], 0, 0, 0);
                acc[i][j] = __builtin_amdgcn_mfma_f32_16x16x32_bf16(a_l[i], b_h[j], acc[i][j], 0, 0, 0);
            }
    }
}

// ---------------------------------------------------------------------------
// Fused stage-1: for weight wi in {gx, theta, phi}:
//   Yt[c][o] = relu(bn(sum_s X[c,s] * W[o,s])), written as hi/lo bf16 planes.
// grid (5, 12, g): x=o-tile(0..4, padded to 640), y = wi*4 + c-tile, z = batch.
// ---------------------------------------------------------------------------
__global__ __launch_bounds__(256) void gemm_s1(
    const u16* __restrict__ Xh, const u16* __restrict__ Xl,
    const u16* __restrict__ W0h, const u16* __restrict__ W0l,
    const u16* __restrict__ W1h, const u16* __restrict__ W1l,
    const u16* __restrict__ W2h, const u16* __restrict__ W2l,
    const float* __restrict__ bn0, const float* __restrict__ bn1,
    const float* __restrict__ bn2,
    u16* __restrict__ Y0h, u16* __restrict__ Y0l,
    u16* __restrict__ Y1h, u16* __restrict__ Y1l,
    u16* __restrict__ Y2h, u16* __restrict__ Y2l)
{
    const int wi = blockIdx.y >> 2;
    const int by = blockIdx.y & 3;
    const int bx = blockIdx.x;
    const int bz = blockIdx.z;
    const u16* Bh = wi == 0 ? W0h : wi == 1 ? W1h : W2h;
    const u16* Bl = wi == 0 ? W0l : wi == 1 ? W1l : W2l;
    const float* bnp = wi == 0 ? bn0 : wi == 1 ? bn1 : bn2;
    u16* Yh = wi == 0 ? Y0h : wi == 1 ? Y1h : Y2h;
    u16* Yl = wi == 0 ? Y0l : wi == 1 ? Y1l : Y2l;

    __shared__ u16 sAh[4096], sAl[4096], sBh[4096], sBl[4096];
    f4 acc[4][4];
    const f4 z4 = {0.f, 0.f, 0.f, 0.f};
#pragma unroll
    for (int i = 0; i < 4; ++i)
#pragma unroll
        for (int j = 0; j < 4; ++j) acc[i][j] = z4;

    gemm_core(Xh, Xl, Bh, Bl, 2304, 2304, bz * 512 + by * 128, bx * 128,
              sAh, sAl, sBh, sBl, acc);

    const int l = threadIdx.x & 63, w = threadIdx.x >> 6;
    const int wr = w >> 1, wc = w & 1;
    const int mb = by * 128 + wr * 64;      // c
    const int nb = bx * 128 + wc * 64;      // o
    const int lm = l & 15;
#pragma unroll
    for (int j = 0; j < 4; ++j) {
        const int o = nb + j * 16 + lm;
        const bool val = (o < 576);
        float sc = 0.f, sh = 0.f;
        if (val) {
            const float gg = bnp[o], be = bnp[576 + o], mm = bnp[1152 + o], vv = bnp[1728 + o];
            sc = gg * rsqrtf(vv + EPSV);
            sh = be - mm * sc;
        }
#pragma unroll
        for (int i = 0; i < 4; ++i) {
            const int c = mb + i * 16 + ((l >> 4) << 2);
#pragma unroll
            for (int r = 0; r < 4; ++r) {
                const float y = val ? fmaxf(acc[i][j][r] * sc + sh, 0.f) : 0.f;
                const u16 h = f2bf(y);
                const u16 lo = f2bf(y - bf2f(h));
                const size_t off = ((size_t)bz * 512 + c + r) * 640 + o;
                Yh[off] = h; Yl[off] = lo;
            }
        }
    }
}

// ---------------------------------------------------------------------------
// Gc[b][c][d] = sum_{o<640} theta_t[b*512+c][o] * phi_t[b*512+d][o]  (pad=0)
// ---------------------------------------------------------------------------
__global__ __launch_bounds__(256) void gemm_gc(
    const u16* __restrict__ Th, const u16* __restrict__ Tl,
    const u16* __restrict__ Ph, const u16* __restrict__ Pl,
    float* __restrict__ Gc)
{
    __shared__ u16 sAh[4096], sAl[4096], sBh[4096], sBl[4096];
    f4 acc[4][4];
    const f4 z4 = {0.f, 0.f, 0.f, 0.f};
#pragma unroll
    for (int i = 0; i < 4; ++i)
#pragma unroll
        for (int j = 0; j < 4; ++j) acc[i][j] = z4;

    const int bz = blockIdx.z;
    gemm_core(Th, Tl, Ph, Pl, 640, 640,
              bz * 512 + blockIdx.y * 128, bz * 512 + blockIdx.x * 128,
              sAh, sAl, sBh, sBl, acc);

    const int l = threadIdx.x & 63, w = threadIdx.x >> 6;
    const int wr = w >> 1, wc = w & 1;
    const int mb = blockIdx.y * 128 + wr * 64, nb = blockIdx.x * 128 + wc * 64;
    float* Cb = Gc + (size_t)bz * 512 * 512;
#pragma unroll
    for (int i = 0; i < 4; ++i)
#pragma unroll
        for (int j = 0; j < 4; ++j) {
            const int c = mb + i * 16 + ((l >> 4) << 2);
            const int d = nb + j * 16 + (l & 15);
#pragma unroll
            for (int r = 0; r < 4; ++r)
                Cb[(size_t)(c + r) * 512 + d] = acc[i][j][r];
        }
}

// ---------------------------------------------------------------------------
// fp32 -> bf16 hi/lo planes (same layout)
// ---------------------------------------------------------------------------
__global__ __launch_bounds__(256) void conv_split(
    const float* __restrict__ in, u16* __restrict__ hi, u16* __restrict__ lo, long n8)
{
    long i = (long)blockIdx.x * 256 + threadIdx.x;
    const long stride = (long)gridDim.x * 256;
    for (; i < n8; i += stride) {
        const float4 a = ((const float4*)in)[2 * i];
        const float4 b = ((const float4*)in)[2 * i + 1];
        const float v[8] = {a.x, a.y, a.z, a.w, b.x, b.y, b.z, b.w};
        unsigned hw[4], lw[4];
#pragma unroll
        for (int k = 0; k < 4; ++k) {
            const u16 h0 = f2bf(v[2 * k]), h1 = f2bf(v[2 * k + 1]);
            const u16 l0 = f2bf(v[2 * k] - bf2f(h0)), l1 = f2bf(v[2 * k + 1] - bf2f(h1));
            hw[k] = (unsigned)h0 | ((unsigned)h1 << 16);
            lw[k] = (unsigned)l0 | ((unsigned)l1 << 16);
        }
        *(uint4*)&hi[8 * i] = make_uint4(hw[0], hw[1], hw[2], hw[3]);
        *(uint4*)&lo[8 * i] = make_uint4(lw[0], lw[1], lw[2], lw[3]);
    }
}

// W [rows][2304] -> padded [640][2304] hi/lo, zero rows >= rows
__global__ __launch_bounds__(256) void conv_w_pad(
    const float* __restrict__ W, u16* __restrict__ hi, u16* __restrict__ lo,
    int rows, long n8)
{
    const long i = (long)blockIdx.x * 256 + threadIdx.x;
    if (i >= n8) return;
    const long e = i * 8;
    const int row = (int)(e / 2304);
    unsigned hw[4] = {0, 0, 0, 0}, lw[4] = {0, 0, 0, 0};
    if (row < rows) {
        const float4 a = ((const float4*)W)[2 * i];
        const float4 b = ((const float4*)W)[2 * i + 1];
        const float v[8] = {a.x, a.y, a.z, a.w, b.x, b.y, b.z, b.w};
#pragma unroll
        for (int k = 0; k < 4; ++k) {
            const u16 h0 = f2bf(v[2 * k]), h1 = f2bf(v[2 * k + 1]);
            const u16 l0 = f2bf(v[2 * k] - bf2f(h0)), l1 = f2bf(v[2 * k + 1] - bf2f(h1));
            hw[k] = (unsigned)h0 | ((unsigned)h1 << 16);
            lw[k] = (unsigned)l0 | ((unsigned)l1 << 16);
        }
    }
    *(uint4*)&hi[8 * i] = make_uint4(hw[0], hw[1], hw[2], hw[3]);
    *(uint4*)&lo[8 * i] = make_uint4(lw[0], lw[1], lw[2], lw[3]);
}

// ---------------------------------------------------------------------------
// row mean over o of ygx hi+lo planes [rows][640] -> out[row] (pads are zero)
// one wave per row
// ---------------------------------------------------------------------------
__global__ __launch_bounds__(256) void row_mean(
    const u16* __restrict__ Yh, const u16* __restrict__ Yl,
    float* __restrict__ out, int rows)
{
    const int l = threadIdx.x & 63;
    const int row = blockIdx.x * 4 + (threadIdx.x >> 6);
    if (row >= rows) return;
    const u16* ph = Yh + (size_t)row * 640;
    const u16* pl = Yl + (size_t)row * 640;
    float s = 0.f;
    struct U8 { u16 u[8]; };
    for (int k = l; k < 80; k += 64) {
        const U8 a = *(const U8*)&ph[k * 8];
        const U8 b = *(const U8*)&pl[k * 8];
#pragma unroll
        for (int e = 0; e < 8; ++e) s += bf2f(a.u[e]) + bf2f(b.u[e]);
    }
    for (int off = 32; off; off >>= 1) s += __shfl_down(s, off, 64);
    if (l == 0) out[row] = s * (1.f / 576.f);
}

// ---------------------------------------------------------------------------
// gg: GG[b][i][d] = relu(bn(sum_{j<512} Wgg[i][j]*Gc[b][d][j]
//                        + sum_{j<512} Wgg[i][512+j]*Gc[b][j][d]))   (fp32)
// ---------------------------------------------------------------------------
__global__ __launch_bounds__(256)
void gemm_gg(const float* __restrict__ Wgg, const float* __restrict__ Gc,
             const float* __restrict__ bn, float* __restrict__ GG,
             int IC, int D)
{
    const int b  = blockIdx.z;
    const int i0 = blockIdx.y * 64;
    const int d0 = blockIdx.x * 64;
    const float* __restrict__ Gb = Gc + (size_t)b * D * D;

    __shared__ float A1s[16][68], B1s[16][68], A2s[16][68], B2s[16][68];

    const int tid  = threadIdx.x;
    const int lrow = tid >> 2;
    const int lc4  = (tid & 3) << 2;
    const int lk   = tid >> 4;
    const int lm4  = (tid & 15) << 2;
    const int tx = tid & 15;
    const int ty = tid >> 4;

    float acc[4][4] = {};

    for (int j0 = 0; j0 < 512; j0 += 16) {
        const float4 a1 = *(const float4*)&Wgg[(size_t)(i0 + lrow) * 1024 + j0 + lc4];
        const float4 a2 = *(const float4*)&Wgg[(size_t)(i0 + lrow) * 1024 + 512 + j0 + lc4];
        const float4 b1 = *(const float4*)&Gb[(size_t)(d0 + lrow) * D + j0 + lc4];
        const float4 b2 = *(const float4*)&Gb[(size_t)(j0 + lk) * D + d0 + lm4];
        __syncthreads();
        A1s[lc4 + 0][lrow] = a1.x; A1s[lc4 + 1][lrow] = a1.y;
        A1s[lc4 + 2][lrow] = a1.z; A1s[lc4 + 3][lrow] = a1.w;
        A2s[lc4 + 0][lrow] = a2.x; A2s[lc4 + 1][lrow] = a2.y;
        A2s[lc4 + 2][lrow] = a2.z; A2s[lc4 + 3][lrow] = a2.w;
        B1s[lc4 + 0][lrow] = b1.x; B1s[lc4 + 1][lrow] = b1.y;
        B1s[lc4 + 2][lrow] = b1.z; B1s[lc4 + 3][lrow] = b1.w;
        *(float4*)&B2s[lk][lm4] = b2;
        __syncthreads();
#pragma unroll
        for (int k = 0; k < 16; ++k) {
            float a1v[4], b1v[4], a2v[4], b2v[4];
            *(float4*)a1v = *(const float4*)&A1s[k][ty << 2];
            *(float4*)b1v = *(const float4*)&B1s[k][tx << 2];
            *(float4*)a2v = *(const float4*)&A2s[k][ty << 2];
            *(float4*)b2v = *(const float4*)&B2s[k][tx << 2];
#pragma unroll
            for (int i = 0; i < 4; ++i)
#pragma unroll
                for (int j = 0; j < 4; ++j)
                    acc[i][j] = fmaf(a1v[i], b1v[j], fmaf(a2v[i], b2v[j], acc[i][j]));
        }
    }

    float* __restrict__ Gout = GG + (size_t)b * IC * D;
#pragma unroll
    for (int i = 0; i < 4; ++i) {
        const int irow = i0 + (ty << 2) + i;
        const float g = bn[irow], be = bn[IC + irow], m = bn[2 * IC + irow], v = bn[3 * IC + irow];
        const float sc = g / sqrtf(v + EPSV);
        const float sh = be - m * sc;
        float4 r;
        r.x = fmaxf(acc[i][0] * sc + sh, 0.f);
        r.y = fmaxf(acc[i][1] * sc + sh, 0.f);
        r.z = fmaxf(acc[i][2] * sc + sh, 0.f);
        r.w = fmaxf(acc[i][3] * sc + sh, 0.f);
        *(float4*)&Gout[(size_t)irow * D + d0 + (tx << 2)] = r;
    }
}

// ---------------------------------------------------------------------------
// gate[b][d] = sigmoid(bn2(sum_o Wc2[o]*relu(bn1(sum_j Wc1[o][j]*yc[b][j][d]))))
// ---------------------------------------------------------------------------
__global__ __launch_bounds__(256)
void gate_kernel(const float* __restrict__ gxc, const float* __restrict__ GG,
                 const float* __restrict__ Wc1, const float* __restrict__ bn1,
                 const float* __restrict__ Wc2, const float* __restrict__ bn2,
                 float* __restrict__ gate, int IC, int D, int OC)
{
    const int b  = blockIdx.y;
    const int d0 = blockIdx.x * 64;

    __shared__ float yc_s[129][64];
    __shared__ float part[4][64];

    const int tid = threadIdx.x;
    for (int idx = tid; idx < 129 * 64; idx += 256) {
        const int j = idx >> 6, d = idx & 63;
        yc_s[j][d] = (j == 0) ? gxc[b * D + d0 + d]
                              : GG[((size_t)b * IC + (j - 1)) * D + d0 + d];
    }
    __syncthreads();

    const int d = tid & 63;
    const int q = tid >> 6;
    float acc2 = 0.f;
    for (int o = q * 16; o < q * 16 + 16; ++o) {
        float s = 0.f;
        const float* __restrict__ w = &Wc1[o * 129];
        for (int j = 0; j < 129; ++j) s = fmaf(w[j], yc_s[j][d], s);
        const float g1 = bn1[o], be1 = bn1[OC + o], m1 = bn1[2 * OC + o], v1 = bn1[3 * OC + o];
        const float sc = g1 / sqrtf(v1 + EPSV);
        const float w1 = fmaxf(s * sc + (be1 - m1 * sc), 0.f);
        acc2 = fmaf(Wc2[o], w1, acc2);
    }
    part[q][d] = acc2;
    __syncthreads();
    if (q == 0) {
        const float s = part[0][d] + part[1][d] + part[2][d] + part[3][d];
        const float g2 = bn2[0], be2 = bn2[1], m2 = bn2[2], v2 = bn2[3];
        const float sc = g2 / sqrtf(v2 + EPSV);
        const float wy = s * sc + (be2 - m2 * sc);
        gate[b * D + d0 + d] = 1.f / (1.f + expf(-wy));
    }
}

// ---------------------------------------------------------------------------
// out = x * (1 + gate[b][c])
// ---------------------------------------------------------------------------
__global__ __launch_bounds__(256)
void final_kernel(const float* __restrict__ x, const float* __restrict__ gate,
                  float* __restrict__ out, long n4, int sp4)
{
    long i = (long)blockIdx.x * blockDim.x + threadIdx.x;
    const long stride = (long)gridDim.x * blockDim.x;
    for (; i < n4; i += stride) {
        float4 v = ((const float4*)x)[i];
        const long bc = i / sp4;
        const float gm = 1.f + gate[bc];
        v.x *= gm; v.y *= gm; v.z *= gm; v.w *= gm;
        ((float4*)out)[i] = v;
    }
}

// ---------------------------------------------------------------------------
extern "C" void kernel_launch(void* const* d_in, const int* in_sizes, int n_in,
                              void* d_out, int out_size, void* d_ws, size_t ws_size,
                              hipStream_t stream)
{
    const float* x        = (const float*)d_in[0];
    const float* W_theta  = (const float*)d_in[1];
    const float* bn_theta = (const float*)d_in[2];
    const float* W_phi    = (const float*)d_in[3];
    const float* bn_phi   = (const float*)d_in[4];
    const float* W_gx     = (const float*)d_in[5];
    const float* bn_gx    = (const float*)d_in[6];
    const float* W_gg     = (const float*)d_in[7];
    const float* bn_gg    = (const float*)d_in[8];
    const float* W_c1     = (const float*)d_in[9];
    const float* bn_c1    = (const float*)d_in[10];
    const float* W_c2     = (const float*)d_in[11];
    const float* bn_c2    = (const float*)d_in[12];
    float* out = (float*)d_out;

    const int B = 32, C = 512, S = 2304, O = 576, OP = 640, IC = 128, OC = 64;

    // ---- d_out arena (all dead before final_kernel rewrites d_out) ----
    u16* yth = (u16*)d_out;                          // [B*512][640]
    u16* ytl = yth + (size_t)B * C * OP;
    u16* yph = ytl + (size_t)B * C * OP;
    u16* ypl = yph + (size_t)B * C * OP;
    float* Gc = (float*)(ypl + (size_t)B * C * OP);  // [B][512][512]
    float* GG = Gc + (size_t)B * C * C;              // [B][128][512]
    u16* Wth = (u16*)(GG + (size_t)B * IC * C);      // 6 W planes [640][2304]
    u16* Wtl = Wth + (size_t)OP * S;
    u16* Wph = Wtl + (size_t)OP * S;
    u16* Wpl = Wph + (size_t)OP * S;
    u16* Wgh = Wpl + (size_t)OP * S;
    u16* Wgl = Wgh + (size_t)OP * S;
    // total arena: 143.5 MB <= 151.0 MB

    // ---- ws: per-group X planes + ygx planes + gxc + gate ----
    const size_t perBatch = (size_t)C * S * 2 * 2 + (size_t)C * OP * 2 * 2; // 6,029,312 B
    const size_t fixedB   = (size_t)2 * B * C * 4 + 1024;
    int g = 1;
    const int cands[6] = {32, 16, 8, 4, 2, 1};
    for (int ci = 0; ci < 6; ++ci)
        if (fixedB + (size_t)cands[ci] * perBatch <= ws_size) { g = cands[ci]; break; }

    u16* Xhi  = (u16*)d_ws;                          // [g*512][2304]
    u16* Xlo  = Xhi + (size_t)g * C * S;
    u16* ygxh = Xlo + (size_t)g * C * S;             // [g*512][640]
    u16* ygxl = ygxh + (size_t)g * C * OP;
    float* gxc  = (float*)(ygxl + (size_t)g * C * OP);  // [B][512]
    float* gate = gxc + (size_t)B * C;                   // [B][512]

    const dim3 blk(256);

    // 1) weights -> padded bf16 hi/lo planes
    const long wN8 = (long)OP * S / 8;               // 184320
    conv_w_pad<<<dim3((unsigned)(wN8 / 256)), blk, 0, stream>>>(W_theta, Wth, Wtl, O, wN8);
    conv_w_pad<<<dim3((unsigned)(wN8 / 256)), blk, 0, stream>>>(W_phi,   Wph, Wpl, O, wN8);
    conv_w_pad<<<dim3((unsigned)(wN8 / 256)), blk, 0, stream>>>(W_gx,    Wgh, Wgl, O, wN8);

    // 2) per batch-group: split X, fused 3-weight stage-1 GEMM, gx row-mean
    for (int b0 = 0; b0 < B; b0 += g) {
        const long xN8 = (long)g * C * S / 8;
        conv_split<<<dim3(2048), blk, 0, stream>>>(x + (size_t)b0 * C * S, Xhi, Xlo, xN8);
        gemm_s1<<<dim3(5, 12, g), blk, 0, stream>>>(
            Xhi, Xlo,
            Wgh, Wgl, Wth, Wtl, Wph, Wpl,
            bn_gx, bn_theta, bn_phi,
            ygxh, ygxl,
            yth + (size_t)b0 * C * OP, ytl + (size_t)b0 * C * OP,
            yph + (size_t)b0 * C * OP, ypl + (size_t)b0 * C * OP);
        row_mean<<<dim3(g * 128), blk, 0, stream>>>(ygxh, ygxl, gxc + (size_t)b0 * C, g * C);
    }

    // 3) Gc = theta_t * phi_t^T (K = 640, zero-padded)
    gemm_gc<<<dim3(4, 4, B), blk, 0, stream>>>(yth, ytl, yph, ypl, Gc);

    // 4) GG (fp32 vector)
    gemm_gg<<<dim3(C / 64, IC / 64, B), blk, 0, stream>>>(W_gg, Gc, bn_gg, GG, IC, C);

    // 5) gate
    gate_kernel<<<dim3(C / 64, B), blk, 0, stream>>>(gxc, GG, W_c1, bn_c1, W_c2, bn_c2,
                                                     gate, IC, C, OC);

    // 6) out = x * (1 + gate)
    final_kernel<<<dim3(2048), blk, 0, stream>>>(x, gate, out,
                                                 (long)B * C * S / 4, S / 4);
}

// Round 3
// 683.985 us; speedup vs baseline: 3.1434x; 1.4564x over previous
//
#include <hip/hip_runtime.h>
#include <cstdint>

#define EPSV 1e-5f
typedef unsigned short u16;
typedef __attribute__((ext_vector_type(8))) short bh8;   // 8 bf16 (4 VGPRs)
typedef __attribute__((ext_vector_type(4))) float f4;

__device__ __forceinline__ float bf2f(u16 h) { return __uint_as_float((unsigned)h << 16); }
__device__ __forceinline__ u16 f2bf(float x) {
    unsigned u = __float_as_uint(x);
    u += 0x7fffu + ((u >> 16) & 1u);          // RNE
    return (u16)(u >> 16);
}

// async global->LDS, 16B per lane; LDS dest = wave-uniform base + lane*16
__device__ __forceinline__ void gl16(const void* g, const void* s) {
    __builtin_amdgcn_global_load_lds(
        reinterpret_cast<const __attribute__((address_space(1))) void*>((uintptr_t)g),
        reinterpret_cast<__attribute__((address_space(3))) void*>((unsigned)(uintptr_t)s),
        16, 0, 0);
}

// ---------------------------------------------------------------------------
// 128x128 NT hi/lo GEMM core (4 waves) — used by gemm_gc.
// ---------------------------------------------------------------------------
__device__ __forceinline__ void gemm_core(
    const u16* __restrict__ Ah, const u16* __restrict__ Al,
    const u16* __restrict__ Bh, const u16* __restrict__ Bl,
    long ldK, int K, int rowA0, int rowB0,
    u16* sAh, u16* sAl, u16* sBh, u16* sBl,
    f4 acc[4][4])
{
    const int tid = threadIdx.x, l = tid & 63, w = tid >> 6;
    const int ch0 = w * 64 + l;
    const int r0 = ch0 >> 2, c0 = (ch0 & 3) << 3;     // staging row/col (q=0)
    const int r1 = r0 + 64;                           // q=1: same col
    const int wr = w >> 1, wc = w & 1;
    const int lk = (l >> 4) << 3, lm = l & 15;
    const char* bA = (const char*)sAh + w * 1024;
    const char* bAl = (const char*)sAl + w * 1024;
    const char* bB = (const char*)sBh + w * 1024;
    const char* bBl = (const char*)sBl + w * 1024;

    for (int s0 = 0; s0 < K; s0 += 32) {
        if (s0) __syncthreads();
        gl16(Ah + (size_t)(rowA0 + r0) * ldK + s0 + c0, bA);
        gl16(Ah + (size_t)(rowA0 + r1) * ldK + s0 + c0, bA + 4096);
        gl16(Al + (size_t)(rowA0 + r0) * ldK + s0 + c0, bAl);
        gl16(Al + (size_t)(rowA0 + r1) * ldK + s0 + c0, bAl + 4096);
        gl16(Bh + (size_t)(rowB0 + r0) * ldK + s0 + c0, bB);
        gl16(Bh + (size_t)(rowB0 + r1) * ldK + s0 + c0, bB + 4096);
        gl16(Bl + (size_t)(rowB0 + r0) * ldK + s0 + c0, bBl);
        gl16(Bl + (size_t)(rowB0 + r1) * ldK + s0 + c0, bBl + 4096);
        __syncthreads();

        bh8 a_h[4], a_l[4], b_h[4], b_l[4];
#pragma unroll
        for (int i = 0; i < 4; ++i) {
            const int ar = (wr * 64 + i * 16 + lm) * 32 + lk;
            const int br = (wc * 64 + i * 16 + lm) * 32 + lk;
            a_h[i] = *(const bh8*)&sAh[ar];
            a_l[i] = *(const bh8*)&sAl[ar];
            b_h[i] = *(const bh8*)&sBh[br];
            b_l[i] = *(const bh8*)&sBl[br];
        }
#pragma unroll
        for (int i = 0; i < 4; ++i)
#pragma unroll
            for (int j = 0; j < 4; ++j) {
                acc[i][j] = __builtin_amdgcn_mfma_f32_16x16x32_bf16(a_h[i], b_h[j], acc[i][j], 0, 0, 0);
                acc[i][j] = __builtin_amdgcn_mfma_f32_16x16x32_bf16(a_h[i], b_l[j], acc[i][j], 0, 0, 0);
                acc[i][j] = __builtin_amdgcn_mfma_f32_16x16x32_bf16(a_l[i], b_h[j], acc[i][j], 0, 0, 0);
            }
    }
}

// ---------------------------------------------------------------------------
// Stage-1 v2: 256(c) x 128(o) tile, 8 waves, 1D grid with chunked XCD swizzle.
// For weight wi in {gx, theta, phi}: Yt[c][o] = relu(bn(sum_s X[c,s]*W[o,s]))
// written as hi/lo bf16 planes [B*512][640].
// Grid: 960 blocks = 32 batch * 2 c-tiles * 15 o-tiles (o fastest in chunk).
// ---------------------------------------------------------------------------
__global__ __launch_bounds__(512) void gemm_s1_v2(
    const u16* __restrict__ Xh, const u16* __restrict__ Xl,
    const u16* __restrict__ W0h, const u16* __restrict__ W0l,
    const u16* __restrict__ W1h, const u16* __restrict__ W1l,
    const u16* __restrict__ W2h, const u16* __restrict__ W2l,
    const float* __restrict__ bn0, const float* __restrict__ bn1,
    const float* __restrict__ bn2,
    u16* __restrict__ Y0h, u16* __restrict__ Y0l,
    u16* __restrict__ Y1h, u16* __restrict__ Y1l,
    u16* __restrict__ Y2h, u16* __restrict__ Y2l)
{
    // bijective chunked XCD swizzle: 960 = 8 * 120
    const int h = blockIdx.x;
    const int orig = (h & 7) * 120 + (h >> 3);
    const int ot = orig % 15;                 // o-tile 0..14 (fastest)
    const int g2 = orig / 15;                 // 0..63
    const int ct = g2 & 1;                    // c-tile 0..1
    const int bz = g2 >> 1;                   // batch 0..31

    const int wi = ot / 5;                    // weight select
    const int otw = ot % 5;                   // o-tile within weight
    const u16* Bh = wi == 0 ? W0h : wi == 1 ? W1h : W2h;
    const u16* Bl = wi == 0 ? W0l : wi == 1 ? W1l : W2l;
    const float* bnp = wi == 0 ? bn0 : wi == 1 ? bn1 : bn2;
    u16* Yh = wi == 0 ? Y0h : wi == 1 ? Y1h : Y2h;
    u16* Yl = wi == 0 ? Y0l : wi == 1 ? Y1l : Y2l;

    __shared__ u16 sAh[256 * 32], sAl[256 * 32];   // 16 KB each
    __shared__ u16 sBh[128 * 32], sBl[128 * 32];   // 8 KB each

    const int tid = threadIdx.x;              // 0..511
    const int w = tid >> 6, l = tid & 63;
    const int srow = tid >> 2;                // staging row 0..127
    const int sc16 = (tid & 3) << 3;          // staging k-offset (elements)

    const int rowA0 = bz * 512 + ct * 256;
    const int rowB0 = otw * 128;

    // hoisted per-thread global element offsets
    const size_t a0off = (size_t)(rowA0 + srow) * 2304 + sc16;
    const size_t a1off = a0off + (size_t)128 * 2304;
    const size_t boff  = (size_t)(rowB0 + srow) * 2304 + sc16;

    // wave-uniform LDS staging bases (each gl16 region = 8 KB = 512 thr * 16B)
    char* const aH0 = (char*)sAh + w * 1024;
    char* const aH1 = (char*)sAh + 8192 + w * 1024;
    char* const aL0 = (char*)sAl + w * 1024;
    char* const aL1 = (char*)sAl + 8192 + w * 1024;
    char* const bH0 = (char*)sBh + w * 1024;
    char* const bL0 = (char*)sBl + w * 1024;

    const int wr = w >> 1, wc = w & 1;        // 4 (c) x 2 (o) wave grid
    const int lk = (l >> 4) << 3, lm = l & 15;

    f4 acc[4][4];
    const f4 z4 = {0.f, 0.f, 0.f, 0.f};
#pragma unroll
    for (int i = 0; i < 4; ++i)
#pragma unroll
        for (int j = 0; j < 4; ++j) acc[i][j] = z4;

    for (int s0 = 0; s0 < 2304; s0 += 32) {
        if (s0) __syncthreads();
        gl16(Xh + a0off + s0, aH0);
        gl16(Xh + a1off + s0, aH1);
        gl16(Xl + a0off + s0, aL0);
        gl16(Xl + a1off + s0, aL1);
        gl16(Bh + boff + s0, bH0);
        gl16(Bl + boff + s0, bL0);
        __syncthreads();

        bh8 a_h[4], a_l[4], b_h[4], b_l[4];
#pragma unroll
        for (int i = 0; i < 4; ++i) {
            const int ar = (wr * 64 + i * 16 + lm) * 32 + lk;
            const int br = (wc * 64 + i * 16 + lm) * 32 + lk;
            a_h[i] = *(const bh8*)&sAh[ar];
            a_l[i] = *(const bh8*)&sAl[ar];
            b_h[i] = *(const bh8*)&sBh[br];
            b_l[i] = *(const bh8*)&sBl[br];
        }
#pragma unroll
        for (int i = 0; i < 4; ++i)
#pragma unroll
            for (int j = 0; j < 4; ++j) {
                acc[i][j] = __builtin_amdgcn_mfma_f32_16x16x32_bf16(a_h[i], b_h[j], acc[i][j], 0, 0, 0);
                acc[i][j] = __builtin_amdgcn_mfma_f32_16x16x32_bf16(a_h[i], b_l[j], acc[i][j], 0, 0, 0);
                acc[i][j] = __builtin_amdgcn_mfma_f32_16x16x32_bf16(a_l[i], b_h[j], acc[i][j], 0, 0, 0);
            }
    }

    // epilogue: bn + relu, hi/lo split, write Y^T [b*512+c][640]
    const int mb = ct * 256 + wr * 64;
    const int nbw = otw * 128 + wc * 64;      // o within weight
#pragma unroll
    for (int j = 0; j < 4; ++j) {
        const int o = nbw + j * 16 + lm;
        const bool val = (o < 576);
        float sc = 0.f, sh = 0.f;
        if (val) {
            const float gg = bnp[o], be = bnp[576 + o], mm = bnp[1152 + o], vv = bnp[1728 + o];
            sc = gg * rsqrtf(vv + EPSV);
            sh = be - mm * sc;
        }
#pragma unroll
        for (int i = 0; i < 4; ++i) {
            const int c = mb + i * 16 + ((l >> 4) << 2);
#pragma unroll
            for (int r = 0; r < 4; ++r) {
                const float y = val ? fmaxf(acc[i][j][r] * sc + sh, 0.f) : 0.f;
                const u16 hh = f2bf(y);
                const u16 lo = f2bf(y - bf2f(hh));
                const size_t off = ((size_t)bz * 512 + c + r) * 640 + o;
                Yh[off] = hh; Yl[off] = lo;
            }
        }
    }
}

// ---------------------------------------------------------------------------
// Gc[b][c][d] = sum_{o<640} theta_t[b*512+c][o] * phi_t[b*512+d][o]  (pad=0)
// 1D grid 512 = 8 * 64, chunked XCD swizzle.
// ---------------------------------------------------------------------------
__global__ __launch_bounds__(256) void gemm_gc(
    const u16* __restrict__ Th, const u16* __restrict__ Tl,
    const u16* __restrict__ Ph, const u16* __restrict__ Pl,
    float* __restrict__ Gc)
{
    const int h = blockIdx.x;
    const int orig = (h & 7) * 64 + (h >> 3);
    const int bx = orig & 3;
    const int by = (orig >> 2) & 3;
    const int bz = orig >> 4;

    __shared__ u16 sAh[4096], sAl[4096], sBh[4096], sBl[4096];
    f4 acc[4][4];
    const f4 z4 = {0.f, 0.f, 0.f, 0.f};
#pragma unroll
    for (int i = 0; i < 4; ++i)
#pragma unroll
        for (int j = 0; j < 4; ++j) acc[i][j] = z4;

    gemm_core(Th, Tl, Ph, Pl, 640, 640,
              bz * 512 + by * 128, bz * 512 + bx * 128,
              sAh, sAl, sBh, sBl, acc);

    const int l = threadIdx.x & 63, w = threadIdx.x >> 6;
    const int wr = w >> 1, wc = w & 1;
    const int mb = by * 128 + wr * 64, nb = bx * 128 + wc * 64;
    float* Cb = Gc + (size_t)bz * 512 * 512;
#pragma unroll
    for (int i = 0; i < 4; ++i)
#pragma unroll
        for (int j = 0; j < 4; ++j) {
            const int c = mb + i * 16 + ((l >> 4) << 2);
            const int d = nb + j * 16 + (l & 15);
#pragma unroll
            for (int r = 0; r < 4; ++r)
                Cb[(size_t)(c + r) * 512 + d] = acc[i][j][r];
        }
}

// ---------------------------------------------------------------------------
// fp32 -> bf16 hi/lo planes
// ---------------------------------------------------------------------------
__global__ __launch_bounds__(256) void conv_split(
    const float* __restrict__ in, u16* __restrict__ hi, u16* __restrict__ lo, long n8)
{
    long i = (long)blockIdx.x * 256 + threadIdx.x;
    const long stride = (long)gridDim.x * 256;
    for (; i < n8; i += stride) {
        const float4 a = ((const float4*)in)[2 * i];
        const float4 b = ((const float4*)in)[2 * i + 1];
        const float v[8] = {a.x, a.y, a.z, a.w, b.x, b.y, b.z, b.w};
        unsigned hw[4], lw[4];
#pragma unroll
        for (int k = 0; k < 4; ++k) {
            const u16 h0 = f2bf(v[2 * k]), h1 = f2bf(v[2 * k + 1]);
            const u16 l0 = f2bf(v[2 * k] - bf2f(h0)), l1 = f2bf(v[2 * k + 1] - bf2f(h1));
            hw[k] = (unsigned)h0 | ((unsigned)h1 << 16);
            lw[k] = (unsigned)l0 | ((unsigned)l1 << 16);
        }
        *(uint4*)&hi[8 * i] = make_uint4(hw[0], hw[1], hw[2], hw[3]);
        *(uint4*)&lo[8 * i] = make_uint4(lw[0], lw[1], lw[2], lw[3]);
    }
}

// W [rows][2304] -> padded [640][2304] hi/lo, zero rows >= rows
__global__ __launch_bounds__(256) void conv_w_pad(
    const float* __restrict__ W, u16* __restrict__ hi, u16* __restrict__ lo,
    int rows, long n8)
{
    const long i = (long)blockIdx.x * 256 + threadIdx.x;
    if (i >= n8) return;
    const long e = i * 8;
    const int row = (int)(e / 2304);
    unsigned hw[4] = {0, 0, 0, 0}, lw[4] = {0, 0, 0, 0};
    if (row < rows) {
        const float4 a = ((const float4*)W)[2 * i];
        const float4 b = ((const float4*)W)[2 * i + 1];
        const float v[8] = {a.x, a.y, a.z, a.w, b.x, b.y, b.z, b.w};
#pragma unroll
        for (int k = 0; k < 4; ++k) {
            const u16 h0 = f2bf(v[2 * k]), h1 = f2bf(v[2 * k + 1]);
            const u16 l0 = f2bf(v[2 * k] - bf2f(h0)), l1 = f2bf(v[2 * k + 1] - bf2f(h1));
            hw[k] = (unsigned)h0 | ((unsigned)h1 << 16);
            lw[k] = (unsigned)l0 | ((unsigned)l1 << 16);
        }
    }
    *(uint4*)&hi[8 * i] = make_uint4(hw[0], hw[1], hw[2], hw[3]);
    *(uint4*)&lo[8 * i] = make_uint4(lw[0], lw[1], lw[2], lw[3]);
}

// ---------------------------------------------------------------------------
// row mean over o of ygx hi+lo planes [rows][640] -> out[row]
// ---------------------------------------------------------------------------
__global__ __launch_bounds__(256) void row_mean(
    const u16* __restrict__ Yh, const u16* __restrict__ Yl,
    float* __restrict__ out, int rows)
{
    const int l = threadIdx.x & 63;
    const int row = blockIdx.x * 4 + (threadIdx.x >> 6);
    if (row >= rows) return;
    const u16* ph = Yh + (size_t)row * 640;
    const u16* pl = Yl + (size_t)row * 640;
    float s = 0.f;
    struct U8 { u16 u[8]; };
    for (int k = l; k < 80; k += 64) {
        const U8 a = *(const U8*)&ph[k * 8];
        const U8 b = *(const U8*)&pl[k * 8];
#pragma unroll
        for (int e = 0; e < 8; ++e) s += bf2f(a.u[e]) + bf2f(b.u[e]);
    }
    for (int off = 32; off; off >>= 1) s += __shfl_down(s, off, 64);
    if (l == 0) out[row] = s * (1.f / 576.f);
}

// ---------------------------------------------------------------------------
// gg: GG[b][i][d] = relu(bn(sum_{j<512} Wgg[i][j]*Gc[b][d][j]
//                        + sum_{j<512} Wgg[i][512+j]*Gc[b][j][d]))   (fp32)
// ---------------------------------------------------------------------------
__global__ __launch_bounds__(256)
void gemm_gg(const float* __restrict__ Wgg, const float* __restrict__ Gc,
             const float* __restrict__ bn, float* __restrict__ GG,
             int IC, int D)
{
    const int b  = blockIdx.z;
    const int i0 = blockIdx.y * 64;
    const int d0 = blockIdx.x * 64;
    const float* __restrict__ Gb = Gc + (size_t)b * D * D;

    __shared__ float A1s[16][68], B1s[16][68], A2s[16][68], B2s[16][68];

    const int tid  = threadIdx.x;
    const int lrow = tid >> 2;
    const int lc4  = (tid & 3) << 2;
    const int lk   = tid >> 4;
    const int lm4  = (tid & 15) << 2;
    const int tx = tid & 15;
    const int ty = tid >> 4;

    float acc[4][4] = {};

    for (int j0 = 0; j0 < 512; j0 += 16) {
        const float4 a1 = *(const float4*)&Wgg[(size_t)(i0 + lrow) * 1024 + j0 + lc4];
        const float4 a2 = *(const float4*)&Wgg[(size_t)(i0 + lrow) * 1024 + 512 + j0 + lc4];
        const float4 b1 = *(const float4*)&Gb[(size_t)(d0 + lrow) * D + j0 + lc4];
        const float4 b2 = *(const float4*)&Gb[(size_t)(j0 + lk) * D + d0 + lm4];
        __syncthreads();
        A1s[lc4 + 0][lrow] = a1.x; A1s[lc4 + 1][lrow] = a1.y;
        A1s[lc4 + 2][lrow] = a1.z; A1s[lc4 + 3][lrow] = a1.w;
        A2s[lc4 + 0][lrow] = a2.x; A2s[lc4 + 1][lrow] = a2.y;
        A2s[lc4 + 2][lrow] = a2.z; A2s[lc4 + 3][lrow] = a2.w;
        B1s[lc4 + 0][lrow] = b1.x; B1s[lc4 + 1][lrow] = b1.y;
        B1s[lc4 + 2][lrow] = b1.z; B1s[lc4 + 3][lrow] = b1.w;
        *(float4*)&B2s[lk][lm4] = b2;
        __syncthreads();
#pragma unroll
        for (int k = 0; k < 16; ++k) {
            float a1v[4], b1v[4], a2v[4], b2v[4];
            *(float4*)a1v = *(const float4*)&A1s[k][ty << 2];
            *(float4*)b1v = *(const float4*)&B1s[k][tx << 2];
            *(float4*)a2v = *(const float4*)&A2s[k][ty << 2];
            *(float4*)b2v = *(const float4*)&B2s[k][tx << 2];
#pragma unroll
            for (int i = 0; i < 4; ++i)
#pragma unroll
                for (int j = 0; j < 4; ++j)
                    acc[i][j] = fmaf(a1v[i], b1v[j], fmaf(a2v[i], b2v[j], acc[i][j]));
        }
    }

    float* __restrict__ Gout = GG + (size_t)b * IC * D;
#pragma unroll
    for (int i = 0; i < 4; ++i) {
        const int irow = i0 + (ty << 2) + i;
        const float g = bn[irow], be = bn[IC + irow], m = bn[2 * IC + irow], v = bn[3 * IC + irow];
        const float sc = g / sqrtf(v + EPSV);
        const float sh = be - m * sc;
        float4 r;
        r.x = fmaxf(acc[i][0] * sc + sh, 0.f);
        r.y = fmaxf(acc[i][1] * sc + sh, 0.f);
        r.z = fmaxf(acc[i][2] * sc + sh, 0.f);
        r.w = fmaxf(acc[i][3] * sc + sh, 0.f);
        *(float4*)&Gout[(size_t)irow * D + d0 + (tx << 2)] = r;
    }
}

// ---------------------------------------------------------------------------
// gate[b][d] = sigmoid(bn2(sum_o Wc2[o]*relu(bn1(sum_j Wc1[o][j]*yc[b][j][d]))))
// ---------------------------------------------------------------------------
__global__ __launch_bounds__(256)
void gate_kernel(const float* __restrict__ gxc, const float* __restrict__ GG,
                 const float* __restrict__ Wc1, const float* __restrict__ bn1,
                 const float* __restrict__ Wc2, const float* __restrict__ bn2,
                 float* __restrict__ gate, int IC, int D, int OC)
{
    const int b  = blockIdx.y;
    const int d0 = blockIdx.x * 64;

    __shared__ float yc_s[129][64];
    __shared__ float part[4][64];

    const int tid = threadIdx.x;
    for (int idx = tid; idx < 129 * 64; idx += 256) {
        const int j = idx >> 6, d = idx & 63;
        yc_s[j][d] = (j == 0) ? gxc[b * D + d0 + d]
                              : GG[((size_t)b * IC + (j - 1)) * D + d0 + d];
    }
    __syncthreads();

    const int d = tid & 63;
    const int q = tid >> 6;
    float acc2 = 0.f;
    for (int o = q * 16; o < q * 16 + 16; ++o) {
        float s = 0.f;
        const float* __restrict__ w = &Wc1[o * 129];
        for (int j = 0; j < 129; ++j) s = fmaf(w[j], yc_s[j][d], s);
        const float g1 = bn1[o], be1 = bn1[OC + o], m1 = bn1[2 * OC + o], v1 = bn1[3 * OC + o];
        const float sc = g1 / sqrtf(v1 + EPSV);
        const float w1 = fmaxf(s * sc + (be1 - m1 * sc), 0.f);
        acc2 = fmaf(Wc2[o], w1, acc2);
    }
    part[q][d] = acc2;
    __syncthreads();
    if (q == 0) {
        const float s = part[0][d] + part[1][d] + part[2][d] + part[3][d];
        const float g2 = bn2[0], be2 = bn2[1], m2 = bn2[2], v2 = bn2[3];
        const float sc = g2 / sqrtf(v2 + EPSV);
        const float wy = s * sc + (be2 - m2 * sc);
        gate[b * D + d0 + d] = 1.f / (1.f + expf(-wy));
    }
}

// ---------------------------------------------------------------------------
// out = x * (1 + gate[b][c])
// ---------------------------------------------------------------------------
__global__ __launch_bounds__(256)
void final_kernel(const float* __restrict__ x, const float* __restrict__ gate,
                  float* __restrict__ out, long n4, int sp4)
{
    long i = (long)blockIdx.x * blockDim.x + threadIdx.x;
    const long stride = (long)gridDim.x * blockDim.x;
    for (; i < n4; i += stride) {
        float4 v = ((const float4*)x)[i];
        const long bc = i / sp4;
        const float gm = 1.f + gate[bc];
        v.x *= gm; v.y *= gm; v.z *= gm; v.w *= gm;
        ((float4*)out)[i] = v;
    }
}

// ---------------------------------------------------------------------------
extern "C" void kernel_launch(void* const* d_in, const int* in_sizes, int n_in,
                              void* d_out, int out_size, void* d_ws, size_t ws_size,
                              hipStream_t stream)
{
    const float* x        = (const float*)d_in[0];
    const float* W_theta  = (const float*)d_in[1];
    const float* bn_theta = (const float*)d_in[2];
    const float* W_phi    = (const float*)d_in[3];
    const float* bn_phi   = (const float*)d_in[4];
    const float* W_gx     = (const float*)d_in[5];
    const float* bn_gx    = (const float*)d_in[6];
    const float* W_gg     = (const float*)d_in[7];
    const float* bn_gg    = (const float*)d_in[8];
    const float* W_c1     = (const float*)d_in[9];
    const float* bn_c1    = (const float*)d_in[10];
    const float* W_c2     = (const float*)d_in[11];
    const float* bn_c2    = (const float*)d_in[12];
    float* out = (float*)d_out;

    const int B = 32, C = 512, S = 2304, O = 576, OP = 640, IC = 128, OC = 64;

    // ---- d_out arena (all dead before final_kernel rewrites d_out) ----
    u16* yth = (u16*)d_out;                          // [B*512][640]
    u16* ytl = yth + (size_t)B * C * OP;
    u16* yph = ytl + (size_t)B * C * OP;
    u16* ypl = yph + (size_t)B * C * OP;
    float* Gc = (float*)(ypl + (size_t)B * C * OP);  // [B][512][512]
    float* GG = Gc + (size_t)B * C * C;              // [B][128][512]
    u16* Wth = (u16*)(GG + (size_t)B * IC * C);      // 6 W planes [640][2304]
    u16* Wtl = Wth + (size_t)OP * S;
    u16* Wph = Wtl + (size_t)OP * S;
    u16* Wpl = Wph + (size_t)OP * S;
    u16* Wgh = Wpl + (size_t)OP * S;
    u16* Wgl = Wgh + (size_t)OP * S;

    // ---- ws: X planes (all batches) + ygx planes + gxc + gate ----
    u16* Xhi  = (u16*)d_ws;                          // [B*512][2304]
    u16* Xlo  = Xhi + (size_t)B * C * S;
    u16* ygxh = Xlo + (size_t)B * C * S;             // [B*512][640]
    u16* ygxl = ygxh + (size_t)B * C * OP;
    float* gxc  = (float*)(ygxl + (size_t)B * C * OP);  // [B][512]
    float* gate = gxc + (size_t)B * C;                   // [B][512]

    const dim3 blk(256);

    // 1) weights -> padded bf16 hi/lo planes
    const long wN8 = (long)OP * S / 8;
    conv_w_pad<<<dim3((unsigned)(wN8 / 256)), blk, 0, stream>>>(W_theta, Wth, Wtl, O, wN8);
    conv_w_pad<<<dim3((unsigned)(wN8 / 256)), blk, 0, stream>>>(W_phi,   Wph, Wpl, O, wN8);
    conv_w_pad<<<dim3((unsigned)(wN8 / 256)), blk, 0, stream>>>(W_gx,    Wgh, Wgl, O, wN8);

    // 2) split X (all batches), fused 3-weight stage-1 GEMM, gx row-mean
    conv_split<<<dim3(2048), blk, 0, stream>>>(x, Xhi, Xlo, (long)B * C * S / 8);
    gemm_s1_v2<<<dim3(960), dim3(512), 0, stream>>>(
        Xhi, Xlo,
        Wgh, Wgl, Wth, Wtl, Wph, Wpl,
        bn_gx, bn_theta, bn_phi,
        ygxh, ygxl, yth, ytl, yph, ypl);
    row_mean<<<dim3(B * 128), blk, 0, stream>>>(ygxh, ygxl, gxc, B * C);

    // 3) Gc = theta_t * phi_t^T (K = 640, zero-padded)
    gemm_gc<<<dim3(512), blk, 0, stream>>>(yth, ytl, yph, ypl, Gc);

    // 4) GG (fp32 vector)
    gemm_gg<<<dim3(C / 64, IC / 64, B), blk, 0, stream>>>(W_gg, Gc, bn_gg, GG, IC, C);

    // 5) gate
    gate_kernel<<<dim3(C / 64, B), blk, 0, stream>>>(gxc, GG, W_c1, bn_c1, W_c2, bn_c2,
                                                     gate, IC, C, OC);

    // 6) out = x * (1 + gate)
    final_kernel<<<dim3(2048), blk, 0, stream>>>(x, gate, out,
                                                 (long)B * C * S / 4, S / 4);
}